// Round 1
// baseline (364.985 us; speedup 1.0000x reference)
//
#include <hip/hip_runtime.h>

#define HW (128*128)

typedef __bf16 bf16x8 __attribute__((ext_vector_type(8)));
typedef float  float4v __attribute__((ext_vector_type(4)));
typedef int    int4v   __attribute__((ext_vector_type(4)));

static __device__ __forceinline__ short f2bf(float f) {
    unsigned u = __float_as_uint(f);
    unsigned r = (u + 0x7FFFu + ((u >> 16) & 1u)) >> 16;
    return (short)(r & 0xFFFFu);
}

static __device__ __forceinline__ int pack2(short a, short b) {
    return (int)((unsigned short)a | ((unsigned)(unsigned short)b << 16));
}

// ---------------------------------------------------------------------------
// Weight repack: W1t [64][160] (k = tap*16+ci, pad 144..159 = 0)
//                W2t [64][64]
//                W3t [288][576] (n = c*24+j, j==23 -> 0; k = tap*64+ci)
// ---------------------------------------------------------------------------
__global__ __launch_bounds__(256) void prep_weights(
    const float* __restrict__ W1, const float* __restrict__ W2,
    const float* __restrict__ W3,
    short* __restrict__ W1t, short* __restrict__ W2t, short* __restrict__ W3t)
{
    int tid = blockIdx.x * 256 + threadIdx.x;
    int stride = gridDim.x * 256;
    for (int i = tid; i < 64*160; i += stride) {
        int n = i / 160, k = i - n*160;
        float v = 0.f;
        if (k < 144) {
            int tap = k >> 4, ci = k & 15;
            int ky = tap / 3, kx = tap - 3*(tap/3);
            v = W1[((n*16 + ci)*3 + ky)*3 + kx];
        }
        W1t[i] = f2bf(v);
    }
    for (int i = tid; i < 64*64; i += stride) W2t[i] = f2bf(W2[i]);
    for (int i = tid; i < 288*576; i += stride) {
        int n = i / 576, k = i - n*576;
        int c = n / 24, j = n - c*24;
        float v = 0.f;
        if (j < 23) {
            int tap = k >> 6, ci = k & 63;
            int ky = tap / 3, kx = tap - 3*(tap/3);
            v = W3[(((c*23 + j)*64 + ci)*3 + ky)*3 + kx];
        }
        W3t[i] = f2bf(v);
    }
}

// ---------------------------------------------------------------------------
// pack z: (B,H,W,16) bf16, ch 0..11 = x at odd(y+x) else 0, ch 12..15 = cond.
// Also initializes logdet output.
// ---------------------------------------------------------------------------
__global__ __launch_bounds__(256) void pack_z(
    const float* __restrict__ x, const float* __restrict__ cond,
    const float* __restrict__ logdet_in,
    short* __restrict__ z, float* __restrict__ logdet_out)
{
    int idx = blockIdx.x * 256 + threadIdx.x;   // 0..262143
    if (blockIdx.x == 0 && threadIdx.x < 16)
        logdet_out[threadIdx.x] = logdet_in[threadIdx.x];
    int b = idx >> 14, rem = idx & 16383;
    int yy = rem >> 7, xx = rem & 127;
    bool frozen = ((yy + xx) & 1) == 1;   // mask==1 at odd (i+j)
    short vs[16];
    #pragma unroll
    for (int c = 0; c < 12; ++c)
        vs[c] = f2bf(frozen ? x[(b*12 + c)*HW + rem] : 0.f);
    #pragma unroll
    for (int c = 0; c < 4; ++c)
        vs[12 + c] = f2bf(cond[(b*4 + c)*HW + rem]);
    int4v lo = { pack2(vs[0],vs[1]),  pack2(vs[2],vs[3]),
                 pack2(vs[4],vs[5]),  pack2(vs[6],vs[7]) };
    int4v hi = { pack2(vs[8],vs[9]),  pack2(vs[10],vs[11]),
                 pack2(vs[12],vs[13]),pack2(vs[14],vs[15]) };
    *(int4v*)(z + idx*16)     = lo;
    *(int4v*)(z + idx*16 + 8) = hi;
}

// ---------------------------------------------------------------------------
// conv1: 3x3, 16 -> 64, implicit GEMM K=160 (padded), one image row / block.
// ---------------------------------------------------------------------------
__global__ __launch_bounds__(256) void conv1_kernel(
    const short* __restrict__ z, const short* __restrict__ W1t,
    const float* __restrict__ b1, short* __restrict__ h1)
{
    __shared__ __align__(16) short Ash[128*40];
    __shared__ __align__(16) short Bsh[64*40];
    int t = threadIdx.x;
    int bid = blockIdx.x;
    int b = bid >> 7, y = bid & 127;
    int lane = t & 63, w = t >> 6;
    int l15 = lane & 15, quad = lane >> 4;

    const float4v z4 = {0.f, 0.f, 0.f, 0.f};
    float4v acc[2][4];
    #pragma unroll
    for (int i = 0; i < 2; ++i)
        #pragma unroll
        for (int j = 0; j < 4; ++j) acc[i][j] = z4;

    for (int s = 0; s < 5; ++s) {
        __syncthreads();
        #pragma unroll
        for (int it = 0; it < 2; ++it) {
            int cc = t + it*256;
            int px = cc >> 2, sub = cc & 3;
            int tr = sub >> 1, q = sub & 1;
            int tap = s*2 + tr;
            int4v v = {0,0,0,0};
            if (tap < 9) {
                int sy = y + tap/3 - 1;
                int sx = px + (tap - 3*(tap/3)) - 1;
                if (sy >= 0 && sy < 128 && sx >= 0 && sx < 128)
                    v = *(const int4v*)(z + (((b<<7)+sy)*128 + sx)*16 + q*8);
            }
            *(int4v*)(Ash + px*40 + tr*16 + q*8) = v;
        }
        {
            int n = t >> 2, q = t & 3;
            *(int4v*)(Bsh + n*40 + q*8) = *(const int4v*)(W1t + n*160 + s*32 + q*8);
        }
        __syncthreads();
        bf16x8 a[2];
        #pragma unroll
        for (int i = 0; i < 2; ++i)
            a[i] = *(const bf16x8*)(Ash + (w*32 + i*16 + l15)*40 + quad*8);
        #pragma unroll
        for (int j = 0; j < 4; ++j) {
            bf16x8 bb = *(const bf16x8*)(Bsh + (j*16 + l15)*40 + quad*8);
            #pragma unroll
            for (int i = 0; i < 2; ++i)
                acc[i][j] = __builtin_amdgcn_mfma_f32_16x16x32_bf16(a[i], bb, acc[i][j], 0, 0, 0);
        }
    }
    int rowbase = ((b<<7) + y) << 7;
    #pragma unroll
    for (int j = 0; j < 4; ++j) {
        float bias = b1[j*16 + l15];
        #pragma unroll
        for (int i = 0; i < 2; ++i)
            #pragma unroll
            for (int r = 0; r < 4; ++r) {
                int px = w*32 + i*16 + quad*4 + r;
                float v = fmaxf(acc[i][j][r] + bias, 0.f);
                h1[(rowbase + px)*64 + j*16 + l15] = f2bf(v);
            }
    }
}

// ---------------------------------------------------------------------------
// conv2: 1x1, 64 -> 64.
// ---------------------------------------------------------------------------
__global__ __launch_bounds__(256) void conv2_kernel(
    const short* __restrict__ h1, const short* __restrict__ W2t,
    const float* __restrict__ b2, short* __restrict__ h2)
{
    __shared__ __align__(16) short Ash[128*40];
    __shared__ __align__(16) short Bsh[64*40];
    int t = threadIdx.x;
    int bid = blockIdx.x;
    int b = bid >> 7, y = bid & 127;
    int lane = t & 63, w = t >> 6;
    int l15 = lane & 15, quad = lane >> 4;
    int rowbase = ((b<<7) + y) << 7;

    const float4v z4 = {0.f, 0.f, 0.f, 0.f};
    float4v acc[2][4];
    #pragma unroll
    for (int i = 0; i < 2; ++i)
        #pragma unroll
        for (int j = 0; j < 4; ++j) acc[i][j] = z4;

    for (int s = 0; s < 2; ++s) {
        __syncthreads();
        #pragma unroll
        for (int it = 0; it < 2; ++it) {
            int cc = t + it*256;
            int px = cc >> 2, q = cc & 3;
            *(int4v*)(Ash + px*40 + q*8) =
                *(const int4v*)(h1 + (rowbase + px)*64 + s*32 + q*8);
        }
        {
            int n = t >> 2, q = t & 3;
            *(int4v*)(Bsh + n*40 + q*8) = *(const int4v*)(W2t + n*64 + s*32 + q*8);
        }
        __syncthreads();
        bf16x8 a[2];
        #pragma unroll
        for (int i = 0; i < 2; ++i)
            a[i] = *(const bf16x8*)(Ash + (w*32 + i*16 + l15)*40 + quad*8);
        #pragma unroll
        for (int j = 0; j < 4; ++j) {
            bf16x8 bb = *(const bf16x8*)(Bsh + (j*16 + l15)*40 + quad*8);
            #pragma unroll
            for (int i = 0; i < 2; ++i)
                acc[i][j] = __builtin_amdgcn_mfma_f32_16x16x32_bf16(a[i], bb, acc[i][j], 0, 0, 0);
        }
    }
    #pragma unroll
    for (int j = 0; j < 4; ++j) {
        float bias = b2[j*16 + l15];
        #pragma unroll
        for (int i = 0; i < 2; ++i)
            #pragma unroll
            for (int r = 0; r < 4; ++r) {
                int px = w*32 + i*16 + quad*4 + r;
                float v = fmaxf(acc[i][j][r] + bias, 0.f);
                h2[(rowbase + px)*64 + j*16 + l15] = f2bf(v);
            }
    }
}

// ---------------------------------------------------------------------------
// conv3 (3x3, 64 -> 276 padded to 288) fused with RQS + logdet reduction.
// Block = one image row (128 px). Wave tile: 64 px x 144 cols (6 channels).
// ---------------------------------------------------------------------------
__global__ __launch_bounds__(256) void conv3_rqs_kernel(
    const short* __restrict__ h2, const short* __restrict__ W3t,
    const float* __restrict__ b3, const float* __restrict__ x,
    float* __restrict__ out, float* __restrict__ logdet_out)
{
    __shared__ __align__(16) char smem[75776];
    short* Ash = (short*)smem;            // [128][40]
    short* Bsh = (short*)(smem + 10240);  // [288][40]

    int t = threadIdx.x;
    int bid = blockIdx.x;
    int b = bid >> 7, y = bid & 127;
    int lane = t & 63, w = t >> 6;
    int l15 = lane & 15, quad = lane >> 4;

    const float4v z4 = {0.f, 0.f, 0.f, 0.f};
    float4v acc[4][9];
    #pragma unroll
    for (int i = 0; i < 4; ++i)
        #pragma unroll
        for (int j = 0; j < 9; ++j) acc[i][j] = z4;

    int pxb = (w >> 1) << 6;      // 0 or 64
    int cb  = (w & 1) * 144;      // 0 or 144

    for (int s = 0; s < 18; ++s) {
        __syncthreads();
        int tap = s >> 1, ci0 = (s & 1) << 5;
        int sy = y + tap/3 - 1;
        int dxo = (tap - 3*(tap/3)) - 1;
        #pragma unroll
        for (int it = 0; it < 2; ++it) {
            int cc = t + it*256;
            int px = cc >> 2, q = cc & 3;
            int sx = px + dxo;
            int4v v = {0,0,0,0};
            if (sy >= 0 && sy < 128 && sx >= 0 && sx < 128)
                v = *(const int4v*)(h2 + (((b<<7)+sy)*128 + sx)*64 + ci0 + q*8);
            *(int4v*)(Ash + px*40 + q*8) = v;
        }
        for (int cc = t; cc < 1152; cc += 256) {
            int n = cc >> 2, q = cc & 3;
            *(int4v*)(Bsh + n*40 + q*8) = *(const int4v*)(W3t + n*576 + s*32 + q*8);
        }
        __syncthreads();
        bf16x8 a[4];
        #pragma unroll
        for (int i = 0; i < 4; ++i)
            a[i] = *(const bf16x8*)(Ash + (pxb + i*16 + l15)*40 + quad*8);
        #pragma unroll
        for (int j = 0; j < 9; ++j) {
            bf16x8 bb = *(const bf16x8*)(Bsh + (cb + j*16 + l15)*40 + quad*8);
            #pragma unroll
            for (int i = 0; i < 4; ++i)
                acc[i][j] = __builtin_amdgcn_mfma_f32_16x16x32_bf16(a[i], bb, acc[i][j], 0, 0, 0);
        }
    }
    __syncthreads();

    // ---------------- epilogue: wave-local transpose + RQS ----------------
    float* scr = (float*)smem + w * 4736;   // 32 x 148 floats per wave
    float ldsum = 0.f;
    int cbch = (w & 1) * 6;

    #pragma unroll
    for (int h = 0; h < 2; ++h) {
        #pragma unroll
        for (int ir = 0; ir < 2; ++ir) {
            int i = h*2 + ir;
            #pragma unroll
            for (int j = 0; j < 9; ++j)
                #pragma unroll
                for (int r = 0; r < 4; ++r)
                    scr[(ir*16 + quad*4 + r)*148 + j*16 + l15] = acc[i][j][r];
        }
        __syncthreads();
        #pragma unroll 1
        for (int tt = 0; tt < 3; ++tt) {
            int task = tt*64 + lane;
            int pxh = task & 31, cidx = task >> 5;     // cidx 0..5
            int c = cbch + cidx;
            int px = pxb + h*32 + pxh;
            const float* P = scr + pxh*148 + cidx*24;
            float pr[24];
            *(float4v*)&pr[0]  = *(const float4v*)(P);
            *(float4v*)&pr[4]  = *(const float4v*)(P + 4);
            *(float4v*)&pr[8]  = *(const float4v*)(P + 8);
            *(float4v*)&pr[12] = *(const float4v*)(P + 12);
            *(float4v*)&pr[16] = *(const float4v*)(P + 16);
            *(float4v*)&pr[20] = *(const float4v*)(P + 20);
            const float* B3 = b3 + c*23;
            float pa[23];
            #pragma unroll
            for (int j = 0; j < 23; ++j) pa[j] = pr[j] + B3[j];

            float xin = x[(b*12 + c)*HW + (y << 7) + px];
            bool frozen = ((y + px) & 1) == 1;
            float xa = frozen ? 0.f : xin;
            float xf = frozen ? xin : 0.f;
            float xc = fminf(fmaxf(xa, -3.f), 3.f);
            bool inside = (xa >= -3.f) && (xa <= 3.f);

            // widths softmax + cumwidths + bin select
            float mw = pa[0];
            #pragma unroll
            for (int j = 1; j < 8; ++j) mw = fmaxf(mw, pa[j]);
            float ew[8]; float sw = 0.f;
            #pragma unroll
            for (int j = 0; j < 8; ++j) { ew[j] = __expf(pa[j] - mw); sw += ew[j]; }
            float Aw = 0.992f / sw;
            float run = 0.f, cwl = -3.f, icw = -3.f, iwid = 1.f;
            int idx = 0;
            #pragma unroll
            for (int j = 0; j < 8; ++j) {
                float wj = fmaf(Aw, ew[j], 0.001f);
                run += wj;
                float cwr = (j == 7) ? 3.f : fmaf(6.f, run, -3.f);
                if (xc >= cwl) { icw = cwl; iwid = cwr - cwl; idx = j; }
                cwl = cwr;
            }
            // heights softmax + cumheights at idx
            float mh = pa[8];
            #pragma unroll
            for (int j = 9; j < 16; ++j) mh = fmaxf(mh, pa[j]);
            float eh[8]; float sh = 0.f;
            #pragma unroll
            for (int j = 0; j < 8; ++j) { eh[j] = __expf(pa[8+j] - mh); sh += eh[j]; }
            float Ah = 0.992f / sh;
            run = 0.f;
            float chl = -3.f, ich = 0.f, ihei = 1.f;
            #pragma unroll
            for (int j = 0; j < 8; ++j) {
                float hj = fmaf(Ah, eh[j], 0.001f);
                run += hj;
                float chr = (j == 7) ? 3.f : fmaf(6.f, run, -3.f);
                if (j == idx) { ich = chl; ihei = chr - chl; }
                chl = chr;
            }
            // derivatives (d[0]=d[8]=1)
            float d0 = 1.f, d1 = 1.f;
            #pragma unroll
            for (int j = 1; j < 8; ++j) {
                float v = pa[15 + j];
                float sp = (v > 15.f) ? v : log1pf(__expf(v));
                float dj = 0.001f + sp;
                if (j == idx)     d0 = dj;
                if (j == idx + 1) d1 = dj;
            }
            float dl = ihei / iwid;
            float th = (xc - icw) / iwid;
            float omt = 1.f - th;
            float t1 = th * omt;
            float num = ihei * (dl*th*th + d0*t1);
            float den = dl + (d0 + d1 - 2.f*dl)*t1;
            float yv = ich + num/den;
            float dnum = dl*dl*(d1*th*th + 2.f*dl*t1 + d0*omt*omt);
            float lad = __logf(dnum) - 2.f*__logf(den);

            out[(b*12 + c)*HW + (y << 7) + px] = xf + (inside ? yv : xa);
            ldsum += inside ? lad : 0.f;
        }
        __syncthreads();
    }
    #pragma unroll
    for (int off = 32; off > 0; off >>= 1)
        ldsum += __shfl_down(ldsum, off, 64);
    if (lane == 0) atomicAdd(logdet_out + b, ldsum);
}

// ---------------------------------------------------------------------------
extern "C" void kernel_launch(void* const* d_in, const int* in_sizes, int n_in,
                              void* d_out, int out_size, void* d_ws, size_t ws_size,
                              hipStream_t stream)
{
    const float* x    = (const float*)d_in[0];
    const float* ld   = (const float*)d_in[1];
    const float* cond = (const float*)d_in[2];
    const float* W1   = (const float*)d_in[3];
    const float* b1   = (const float*)d_in[4];
    const float* W2   = (const float*)d_in[5];
    const float* b2   = (const float*)d_in[6];
    const float* W3   = (const float*)d_in[7];
    const float* b3   = (const float*)d_in[8];
    float* out = (float*)d_out;
    char* ws = (char*)d_ws;

    short* z   = (short*)(ws);                 //  8,388,608 B
    short* h1  = (short*)(ws + 8388608);       // 33,554,432 B
    short* h2  = (short*)(ws + 41943040);      // 33,554,432 B
    short* W1t = (short*)(ws + 75497472);      //     20,480 B
    short* W2t = (short*)(ws + 75517952);      //      8,192 B
    short* W3t = (short*)(ws + 75526144);      //    331,776 B
    float* ldout = out + 12*HW*16;             // logdet at end of out

    prep_weights<<<dim3(256), dim3(256), 0, stream>>>(W1, W2, W3, W1t, W2t, W3t);
    pack_z<<<dim3(1024), dim3(256), 0, stream>>>(x, cond, ld, z, ldout);
    conv1_kernel<<<dim3(2048), dim3(256), 0, stream>>>(z, W1t, b1, h1);
    conv2_kernel<<<dim3(2048), dim3(256), 0, stream>>>(h1, W2t, b2, h2);
    conv3_rqs_kernel<<<dim3(2048), dim3(256), 0, stream>>>(h2, W3t, b3, x, out, ldout);
}